// Round 2
// baseline (734.013 us; speedup 1.0000x reference)
//
#include <hip/hip_runtime.h>
#include <math.h>

#define N_TOK  16384
#define DIM    4096
#define NE     64
#define CAP    640
#define TM     64
#define KC     64
#define NTILES (N_TOK / TM)   // 256

// ws layout:
// [0,256):                     counts (64 int, zeroed per call)
// [256, 256+128K):             ws_idx   (int,   N*2)
// [256+128K, 256+256K):        ws_probs (float, N*2)
// [262400, ...):               partials (KS * N * 64 floats)

// GEMM: logits[t][e] = sum_k x[t][k] * W[e][k], k-split into KS partials.
// Per block: 64 tokens x 64 experts. 4 waves; wave w -> experts [16w,16w+16),
// lane l -> token t_base+l. W operand is wave-uniform -> scalar loads (SGPR),
// x staged in LDS with XOR-swizzled float4 blocks (conflict-free b128 reads).
template<int KS>
__global__ __launch_bounds__(256, 4) void gemm_logits_kernel(
    const float* __restrict__ x, const float* __restrict__ W,
    float* __restrict__ partials) {
  const int tile   = blockIdx.x % NTILES;
  const int split  = blockIdx.x / NTILES;
  const int klen   = DIM / KS;
  const int k0     = split * klen;
  const int t_base = tile * TM;

  __shared__ float xs[TM * KC];  // 16 KB, swizzled: (tok,k) -> tok*64 + ((k>>2)^(tok&15))*4 + (k&3)

  const int tid  = threadIdx.x;
  const int lane = tid & 63;
  const int wave = __builtin_amdgcn_readfirstlane(tid >> 6);
  const int e0   = wave * 16;

  const int s_tok = tid >> 2;  // 0..63
  const int s_k4  = tid & 3;   // 0..3
  const float* xrow = x + (size_t)(t_base + s_tok) * DIM + k0;

  float acc[16];
#pragma unroll
  for (int i = 0; i < 16; ++i) acc[i] = 0.f;

  for (int kc = 0; kc < klen; kc += KC) {
    // stage x tile: 64 tokens x 64 k (each thread: 4 float4 loads/stores)
#pragma unroll
    for (int i = 0; i < 4; ++i) {
      const int k4 = s_k4 + i * 4;  // 0..15
      const float4 v = *(const float4*)(xrow + kc + k4 * 4);
      *(float4*)&xs[s_tok * KC + ((k4 ^ (s_tok & 15)) << 2)] = v;
    }
    __syncthreads();
    const float* wbase = W + k0 + kc;
#pragma unroll
    for (int q = 0; q < 16; ++q) {  // 16 sub-chunks of 4 k
      const float4 xv = *(const float4*)&xs[lane * KC + ((q ^ (lane & 15)) << 2)];
#pragma unroll
      for (int e = 0; e < 16; ++e) {
        // wave-uniform address -> s_load_dwordx4; SGPR operand in v_fma
        const float4 wv = *(const float4*)(wbase + (size_t)(e0 + e) * DIM + q * 4);
        acc[e] = fmaf(xv.x, wv.x, acc[e]);
        acc[e] = fmaf(xv.y, wv.y, acc[e]);
        acc[e] = fmaf(xv.z, wv.z, acc[e]);
        acc[e] = fmaf(xv.w, wv.w, acc[e]);
      }
    }
    __syncthreads();
  }

  // partials[split][token][expert]
  float* outp = partials + (size_t)split * N_TOK * NE + (size_t)(t_base + lane) * NE + e0;
#pragma unroll
  for (int i = 0; i < 4; ++i)
    *(float4*)(outp + i * 4) = make_float4(acc[i * 4], acc[i * 4 + 1], acc[i * 4 + 2], acc[i * 4 + 3]);
}

template<int KS>
__global__ __launch_bounds__(64) void route_kernel(
    const float* __restrict__ partials,
    float* __restrict__ out, int* __restrict__ ws_idx,
    float* __restrict__ ws_probs, int* __restrict__ counts) {
  __shared__ int cnt[NE];
  const int tid = threadIdx.x;
  cnt[tid] = 0;
  __syncthreads();
  const int t = blockIdx.x * 64 + tid;

  // top-2 with jax.lax.top_k tie semantics (lower index wins on equality)
  float b1 = -INFINITY, b2 = -INFINITY;
  int i1 = 0, i2 = 0;
#pragma unroll
  for (int e = 0; e < NE; e += 4) {
    float4 s = *(const float4*)(partials + (size_t)t * NE + e);
#pragma unroll
    for (int sp = 1; sp < KS; ++sp) {
      const float4 v = *(const float4*)(partials + (size_t)sp * N_TOK * NE + (size_t)t * NE + e);
      s.x += v.x; s.y += v.y; s.z += v.z; s.w += v.w;
    }
    const float vv[4] = {s.x, s.y, s.z, s.w};
#pragma unroll
    for (int j = 0; j < 4; ++j) {
      const float v = vv[j];
      const int idx = e + j;
      if (v > b1)      { b2 = b1; i2 = i1; b1 = v; i1 = idx; }
      else if (v > b2) { b2 = v; i2 = idx; }
    }
  }
  // softmax over the two kept scores (max-subtracted, like jax.nn.softmax)
  const float ed = expf(b2 - b1);
  const float p1 = 1.0f / (1.0f + ed);
  const float p2 = ed / (1.0f + ed);

  out[(size_t)t * 2]     = p1;
  out[(size_t)t * 2 + 1] = p2;
  out[(size_t)N_TOK * 2 + t * 2]     = (float)i1;  // indices stored as f32
  out[(size_t)N_TOK * 2 + t * 2 + 1] = (float)i2;
  ws_idx[t * 2] = i1;  ws_idx[t * 2 + 1] = i2;
  ws_probs[t * 2] = p1; ws_probs[t * 2 + 1] = p2;

  atomicAdd(&cnt[i1], 1);
  atomicAdd(&cnt[i2], 1);
  __syncthreads();
  atomicAdd(&counts[tid], cnt[tid]);
}

__global__ __launch_bounds__(256) void capacity_kernel(
    const int* __restrict__ counts, const int* __restrict__ ws_idx,
    const float* __restrict__ ws_probs, float* __restrict__ out) {
  const int e = blockIdx.x;
  const int cnt = counts[e];
  if (threadIdx.x == 0) out[(size_t)N_TOK * 4 + e] = (float)cnt;
  if (cnt <= CAP) return;  // cold path: never taken for this input (max count ~ +5.7 sigma below CAP)
  for (int i = threadIdx.x; i < N_TOK * 2; i += 256) {
    if (ws_idx[i] != e) continue;
    const float p = ws_probs[i];
    const int tok = i >> 1;
    int rank = 0;
    for (int j = 0; j < N_TOK * 2; ++j) {
      if (ws_idx[j] != e) continue;
      const float q = ws_probs[j];
      if (q > p || (q == p && (j >> 1) < tok)) ++rank;
    }
    if (rank >= CAP) {
      out[i] = 0.0f;                                   // dropped prob
      out[(size_t)N_TOK * 2 + i] = 2147483648.0f;      // INT32_MAX as f32
    }
  }
}

extern "C" void kernel_launch(void* const* d_in, const int* in_sizes, int n_in,
                              void* d_out, int out_size, void* d_ws, size_t ws_size,
                              hipStream_t stream) {
  const float* x = (const float*)d_in[0];
  const float* W = (const float*)d_in[1];
  float* out = (float*)d_out;

  char* ws = (char*)d_ws;
  int*   counts   = (int*)ws;
  int*   ws_idx   = (int*)(ws + 256);
  float* ws_probs = (float*)(ws + 256 + (size_t)N_TOK * 2 * 4);
  float* partials = (float*)(ws + 262400);

  const size_t base = 262400;
  const size_t per  = (size_t)N_TOK * NE * 4;  // 4 MB per K-split partial
  int ks = 1;
  if      (ws_size >= base + 8 * per) ks = 8;
  else if (ws_size >= base + 4 * per) ks = 4;
  else if (ws_size >= base + 2 * per) ks = 2;

  hipMemsetAsync(counts, 0, NE * sizeof(int), stream);
  switch (ks) {
    case 8:
      gemm_logits_kernel<8><<<NTILES * 8, 256, 0, stream>>>(x, W, partials);
      route_kernel<8><<<N_TOK / 64, 64, 0, stream>>>(partials, out, ws_idx, ws_probs, counts);
      break;
    case 4:
      gemm_logits_kernel<4><<<NTILES * 4, 256, 0, stream>>>(x, W, partials);
      route_kernel<4><<<N_TOK / 64, 64, 0, stream>>>(partials, out, ws_idx, ws_probs, counts);
      break;
    case 2:
      gemm_logits_kernel<2><<<NTILES * 2, 256, 0, stream>>>(x, W, partials);
      route_kernel<2><<<N_TOK / 64, 64, 0, stream>>>(partials, out, ws_idx, ws_probs, counts);
      break;
    default:
      gemm_logits_kernel<1><<<NTILES * 1, 256, 0, stream>>>(x, W, partials);
      route_kernel<1><<<N_TOK / 64, 64, 0, stream>>>(partials, out, ws_idx, ws_probs, counts);
      break;
  }
  capacity_kernel<<<NE, 256, 0, stream>>>(counts, ws_idx, ws_probs, out);
}